// Round 6
// baseline (41.007 us; speedup 1.0000x reference)
//
#include <hip/hip_runtime.h>
#include <hip/hip_bf16.h>

// FDLT: out[b,m,l] = sum_k psiHat[b,m,k] * Em[m][k][l]   (fp32 in/out)
//   Em[m][k][l] = Cm[m] * sum_n XF_sel(m)[k][n] * Dm[l][n],  n in 0..63
// B=64, M=127, 2B=128, BATCH=512. Em stored bf16 [m][l][k].
// Round 6: LDS/barriers removed everywhere.
//  k0 dm_dense: COO -> dense global Dm[127*64][64] fp32 (2MB, L2-resident)
//  k1 build_Em: uniform-address Dm loads (no LDS, no bsearch, no barrier)
//  k2 fdlt_gemm: fragments straight from global (no LDS, no barrier)

#define B_     64
#define M_     127
#define TWOB_  128

using bf16x8 = __attribute__((ext_vector_type(8))) short;  // 8 bf16 (4 VGPR)
using f32x4  = __attribute__((ext_vector_type(4))) float;

__device__ inline short f2bf(float x) {
    __hip_bfloat16 h = __float2bfloat16(x);
    return *reinterpret_cast<short*>(&h);
}

// ---------------------------------------------------------------------------
// Kernel 0: densify COO. One wave per output row r = m*64+l (8128 rows).
// Row ids in COO are exactly r and sorted; nnz per row <= 64 (n <= l <= 63).
// lo via 13-step wave-uniform bsearch; then lane i probes entry lo+i in ONE
// parallel load; scatter through a 64-float LDS slot; coalesced row store.
// ---------------------------------------------------------------------------
__global__ __launch_bounds__(256) void dm_dense(
    const float* __restrict__ Dval,
    const int*   __restrict__ Drow,
    const int*   __restrict__ Dcol,
    int nnz,
    float* __restrict__ Dm)
{
    __shared__ float buf[4][B_];
    const int t    = threadIdx.x;
    const int w    = t >> 6;
    const int lane = t & 63;
    const int r    = blockIdx.x * 4 + w;        // 0..8127
    const int m    = r >> 6;

    // first index with Drow >= r (wave-uniform chain)
    int a = 0, b = nnz;
    while (a < b) { int mid = (a + b) >> 1; if (Drow[mid] < r) a = mid + 1; else b = mid; }

    buf[w][lane] = 0.f;

    int   n = -1;
    float v = 0.f;
    int i = a + lane;
    if (i < nnz && Drow[i] == r) {              // segment length <= 64
        n = Dcol[i] - m * TWOB_;
        v = Dval[i];
    }
    __syncthreads();
    if (n >= 0) buf[w][n] = v;
    __syncthreads();
    Dm[(size_t)r * B_ + lane] = buf[w][lane];
}

// ---------------------------------------------------------------------------
// Kernel 1: Em_bf16[m][l][k] = bf16(Cm[m] * sum_n XF[k][n] * Dm[m*64+l][n]).
// Grid (8, 127) x 128 thr. j (=l-l0) loop is BLOCK-uniform -> Dm float4 loads
// are uniform-address (1 L2 line per instr, broadcast). XF row preloaded into
// 16 float4 registers. 8 independent acc chains (q outer, j inner = ILP 8).
// No LDS, no barrier, no bsearch.
// ---------------------------------------------------------------------------
__global__ __launch_bounds__(128) void build_Em(
    const float* __restrict__ Cm,
    const float* __restrict__ XFc,
    const float* __restrict__ XFs,
    const float* __restrict__ Dm,
    __hip_bfloat16* __restrict__ Em)
{
    const int m  = blockIdx.y;
    const int l0 = blockIdx.x * 8;
    const int k  = threadIdx.x;                 // 0..127

    const float* __restrict__ XF = (m & 1) ? XFc : XFs;
    const float cm = Cm[m];

    const float4* __restrict__ XFrow = reinterpret_cast<const float4*>(XF + k * TWOB_);
    float4 xf[16];
    #pragma unroll
    for (int q = 0; q < 16; ++q) xf[q] = XFrow[q];

    const float4* __restrict__ dmb =
        reinterpret_cast<const float4*>(Dm + (size_t)(m * B_ + l0) * B_);  // 8 rows x 16 quads

    float acc[8] = {};
    #pragma unroll
    for (int q = 0; q < 16; ++q) {
        #pragma unroll
        for (int j = 0; j < 8; ++j) {
            float4 d = dmb[j * 16 + q];          // block-uniform address
            acc[j] += xf[q].x * d.x + xf[q].y * d.y + xf[q].z * d.z + xf[q].w * d.w;
        }
    }
    #pragma unroll
    for (int j = 0; j < 8; ++j)
        Em[(size_t)(m * B_ + l0 + j) * TWOB_ + k] = __float2bfloat16(cm * acc[j]);
}

// ---------------------------------------------------------------------------
// Kernel 2: per (m, batch-tile): out[64l x 64b] = E[64l x 128k] @ A[128k x 64b]
// NO LDS, NO barrier: fragments loaded directly from global.
//   af (A-op, rows=l): Em[m][w*16+lr][ks*32+lg*8 ..+8]   16B, L2-hot per XCD
//   bf (B-op, cols=b): psiHat[b0+nt*16+lr][m][ks*32+lg*8 ..+8] 2x16B, cvt bf16
// XCD mapping: m = (bid&7) + 8*((bid>>3)&15) -> 16 Em matrices (256KB) per XCD.
// D layout: col=lane&15=b, row=lg*4+reg=l -> float4 store of 4 consecutive l.
// ---------------------------------------------------------------------------
__global__ __launch_bounds__(256, 4) void fdlt_gemm(
    const float* __restrict__ psiHat,
    const __hip_bfloat16* __restrict__ Em,
    float* __restrict__ out)
{
    const int bid  = blockIdx.x;
    const int xcd  = bid & 7;
    const int rest = bid >> 3;
    const int m    = xcd + ((rest & 15) << 3);
    const int tile = rest >> 4;
    if (m >= M_) return;                        // 8 guard blocks, uniform exit
    const int b0 = tile * 64;

    const int t    = threadIdx.x;
    const int w    = t >> 6;                    // wave's l-block [w*16, w*16+16)
    const int lane = t & 63;
    const int lr   = lane & 15;
    const int lg   = lane >> 4;

    f32x4 acc[4];
    #pragma unroll
    for (int nt = 0; nt < 4; ++nt) acc[nt] = (f32x4){0.f, 0.f, 0.f, 0.f};

    const __hip_bfloat16* __restrict__ ebase =
        Em + (size_t)m * (B_ * TWOB_) + (w * 16 + lr) * TWOB_;

    #pragma unroll
    for (int ks = 0; ks < 4; ++ks) {
        bf16x8 af = *reinterpret_cast<const bf16x8*>(ebase + ks * 32 + lg * 8);
        #pragma unroll
        for (int nt = 0; nt < 4; ++nt) {
            const float* __restrict__ ap =
                psiHat + ((size_t)(b0 + nt * 16 + lr) * M_ + m) * TWOB_ + ks * 32 + lg * 8;
            f32x4 p0 = *reinterpret_cast<const f32x4*>(ap);
            f32x4 p1 = *reinterpret_cast<const f32x4*>(ap + 4);
            bf16x8 bf;
            bf[0] = f2bf(p0[0]); bf[1] = f2bf(p0[1]); bf[2] = f2bf(p0[2]); bf[3] = f2bf(p0[3]);
            bf[4] = f2bf(p1[0]); bf[5] = f2bf(p1[1]); bf[6] = f2bf(p1[2]); bf[7] = f2bf(p1[3]);
            acc[nt] = __builtin_amdgcn_mfma_f32_16x16x32_bf16(af, bf, acc[nt], 0, 0, 0);
        }
    }

    #pragma unroll
    for (int nt = 0; nt < 4; ++nt) {
        int b = b0 + nt * 16 + lr;
        float4 v;
        v.x = acc[nt][0]; v.y = acc[nt][1]; v.z = acc[nt][2]; v.w = acc[nt][3];
        *reinterpret_cast<float4*>(out + ((size_t)b * M_ + m) * B_ + w * 16 + lg * 4) = v;
    }
}

extern "C" void kernel_launch(void* const* d_in, const int* in_sizes, int n_in,
                              void* d_out, int out_size, void* d_ws, size_t ws_size,
                              hipStream_t stream) {
    const float* psiHat = (const float*)d_in[0];
    const float* Cm     = (const float*)d_in[1];
    const float* XFc    = (const float*)d_in[2];
    const float* XFs    = (const float*)d_in[3];
    const float* Dval   = (const float*)d_in[4];
    const int*   Drow   = (const int*)d_in[5];
    const int*   Dcol   = (const int*)d_in[6];
    const int nnz = in_sizes[4];

    // ws layout: [0, 2,080,768) Em bf16; [2,080,768, 4,161,536) Dm fp32.
    __hip_bfloat16* Em = (__hip_bfloat16*)d_ws;
    float* Dm = (float*)((char*)d_ws + (size_t)M_ * B_ * TWOB_ * sizeof(__hip_bfloat16));

    dm_dense<<<dim3((M_ * B_) / 4), dim3(256), 0, stream>>>(Dval, Drow, Dcol, nnz, Dm);
    build_Em<<<dim3(8, M_), dim3(128), 0, stream>>>(Cm, XFc, XFs, Dm, Em);
    fdlt_gemm<<<dim3(1024), dim3(256), 0, stream>>>(psiHat, Em, (float*)d_out);
}